// Round 14
// baseline (929.652 us; speedup 1.0000x reference)
//
#include <hip/hip_runtime.h>

#define NB 32
#define NZ 100
#define ST 20
#define HID 128
#define HW 32
#define PIX 1024
#define STEPS 64
#define TH 0.1f
#define SCL 0.0625f     // 1/16 stored-value scaling (power of 2)
#define ISCL 16.0f
#define CPAD 24         // channel stride in split-state storage (20 + 4 pad)

typedef _Float16 half8  __attribute__((ext_vector_type(8)));
typedef _Float16 half4v __attribute__((ext_vector_type(4)));
typedef float    floatx4 __attribute__((ext_vector_type(4)));

// perceive GEMM K layout: k = q*24 + c  (q=dy*3+dx in 0..8, c in 0..23, pad from 20)
#define NKS1 7
#define PK 136          // perc/hid LDS row stride

// 4-row block geometry
#define RB 4            // output rows per block
#define TPX 204         // tile pixels with halo 1: 6 rows x 34 cols
#define OPX 128         // output pixels per block (4 x 32)

// dynamic LDS layout (bytes, all 16B-aligned)
#define OFF_BCH0  0                       // 288 f32  (8 x 36, halo 2)
#define OFF_M4    (OFF_BCH0 + 1152)       // 208 f32  (204 used)
#define OFF_TTH   (OFF_M4 + 832)          // 4896 halfs (204 x 24)
#define OFF_TTL   (OFF_TTH + 9792)
#define OFF_Z16   (OFF_TTL + 9792)        // 8 halfs
#define OFF_PH    (OFF_Z16 + 16)          // 17408 halfs (128 x 136)
#define OFF_PL    (OFF_PH + 34816)
#define LDS_BYTES (OFF_PL + 34816)        // = 91216

// ---------------------------------------------------------------------------
// init: init_hidden scattered to center, written as split fp16 (value/16).
__global__ __launch_bounds__(64) void init_state_kernel(
    const float* __restrict__ z, const float* __restrict__ w1,
    const float* __restrict__ b1, const float* __restrict__ w2,
    const float* __restrict__ b2, _Float16* __restrict__ Bh,
    _Float16* __restrict__ Bl, unsigned char* __restrict__ M)
{
    __shared__ float zs[NZ];
    __shared__ float h1[50];
    const int n = blockIdx.x;
    const int t = threadIdx.x;
    for (int i = t; i < NZ; i += 64) zs[i] = z[n * NZ + i];
    __syncthreads();
    if (t < 50) {
        float a = b1[t];
        for (int i = 0; i < NZ; ++i) a += w1[t * NZ + i] * zs[i];
        h1[t] = fmaxf(a, 0.f);
    }
    __syncthreads();
    const int gp = 16 * HW + 16;                 // center pixel
    if (t < ST - 1) {
        float a = b2[t];
        for (int j = 0; j < 50; ++j) a += w2[t * 50 + j] * h1[j];
        float vs = a * SCL;
        _Float16 hi = (_Float16)vs;
        Bh[(size_t)n * PIX * CPAD + gp * CPAD + (t + 1)] = hi;
        Bl[(size_t)n * PIX * CPAD + gp * CPAD + (t + 1)] = (_Float16)(vs - (float)hi);
    }
    if (t == 63) {
        Bh[(size_t)n * PIX * CPAD + gp * CPAD] = (_Float16)(0.5f * SCL);  // exact
        Bl[(size_t)n * PIX * CPAD + gp * CPAD] = (_Float16)0.f;
    }
    for (int i = t; i < PIX; i += 64) M[n * PIX + i] = 1;
}

// ---------------------------------------------------------------------------
// Repack weights into MFMA A-fragment order as fp16 hi/lo pairs.
__global__ __launch_bounds__(256) void repack_kernel(
    const float* __restrict__ Wp, const float* __restrict__ W1,
    const float* __restrict__ W2,
    _Float16* __restrict__ WpRh, _Float16* __restrict__ WpRl,
    _Float16* __restrict__ W1Rh, _Float16* __restrict__ W1Rl,
    _Float16* __restrict__ W2Rh, _Float16* __restrict__ W2Rl)
{
    int e = blockIdx.x * 256 + threadIdx.x;
    if (e < 28672) {
        int j = e & 7, lane = (e >> 3) & 63, t2 = e >> 9;   // t2 = w*7+ks
        int ks = t2 % 7, w = t2 / 7;
        int m = w * 16 + (lane & 15);
        int k = ks * 32 + ((lane >> 4) << 3) + j;
        int q = k / 24, c = k - q * 24;
        float v = (q < 9 && c < ST) ? Wp[m * 180 + c * 9 + q] : 0.f;
        _Float16 hi = (_Float16)v;
        WpRh[e] = hi; WpRl[e] = (_Float16)(v - (float)hi);
    } else if (e < 45056) {
        int e2 = e - 28672;
        int j = e2 & 7, lane = (e2 >> 3) & 63, t2 = e2 >> 9; // t2 = w*4+ks
        int ks = t2 & 3, w = t2 >> 2;
        int m = w * 16 + (lane & 15);
        int k = ks * 32 + ((lane >> 4) << 3) + j;
        float v = W1[m * 128 + k];
        _Float16 hi = (_Float16)v;
        W1Rh[e2] = hi; W1Rl[e2] = (_Float16)(v - (float)hi);
    } else if (e < 49152) {
        int e3 = e - 45056;
        int j = e3 & 7, lane = (e3 >> 3) & 63, t2 = e3 >> 9; // t2 = mt*4+ks
        int ks = t2 & 3, mt = t2 >> 2;
        int m = mt * 16 + (lane & 15);
        int k = ks * 32 + ((lane >> 4) << 3) + j;
        float v = (m < ST) ? W2[m * 128 + k] : 0.f;
        _Float16 hi = (_Float16)v;
        W2Rh[e3] = hi; W2Rl[e3] = (_Float16)(v - (float)hi);
    }
}

// ---------------------------------------------------------------------------
// u0 = b2 + W2 @ relu(b1 + W1 @ bp): exact S' of a dead region (split fp16 /16).
__global__ __launch_bounds__(128) void u0_kernel(
    const float* __restrict__ bp, const float* __restrict__ W1,
    const float* __restrict__ b1, const float* __restrict__ W2,
    const float* __restrict__ b2,
    _Float16* __restrict__ u0h, _Float16* __restrict__ u0l)
{
    __shared__ float h[128];
    const int t = threadIdx.x;
    float a = b1[t];
    for (int i = 0; i < HID; ++i) a += W1[t * HID + i] * bp[i];
    h[t] = fmaxf(a, 0.f);
    __syncthreads();
    if (t < CPAD) {
        float u = 0.f;
        if (t < ST) {
            u = b2[t];
            for (int j = 0; j < HID; ++j) u += W2[t * HID + j] * h[j];
        }
        float us = u * SCL;
        _Float16 hi = (_Float16)us;
        u0h[t] = hi;
        u0l[t] = (_Float16)(us - (float)hi);
    }
}

// ---------------------------------------------------------------------------
// Fused CA step, 4-row blocks (128 px), 1 block/CU, dynamic LDS ~89 KB.
// R14 = R12 arithmetic (bit-identical product order) with weights amortized
// over 2x pixels: A-traffic per CU-step halves (L2 broadcast was binding).
// G1/G2: 2m x 4n per wave; G3: 1m x 2n per wave. Grid (image, strip8):
// id%8 = n%8 -> all 8 strips of an image on one XCD.
__global__ __launch_bounds__(512, 2) void ca_step_kernel(
    const _Float16* __restrict__ Bnh, const _Float16* __restrict__ Bnl,
    const unsigned char* __restrict__ Min,
    _Float16* __restrict__ Boh, _Float16* __restrict__ Bol,
    unsigned char* __restrict__ Mout,
    const _Float16* __restrict__ WpRh, const _Float16* __restrict__ WpRl,
    const float* __restrict__ bp,
    const _Float16* __restrict__ W1Rh, const _Float16* __restrict__ W1Rl,
    const float* __restrict__ b1,
    const _Float16* __restrict__ W2Rh, const _Float16* __restrict__ W2Rl,
    const float* __restrict__ b2,
    const _Float16* __restrict__ u0h, const _Float16* __restrict__ u0l)
{
    extern __shared__ __align__(16) char smem[];
    float* bch0 = (float*)(smem + OFF_BCH0);          // 8 x 36, halo 2
    float* m4   = (float*)(smem + OFF_M4);            // 6 x 34, halo 1
    _Float16* tTh = (_Float16*)(smem + OFF_TTH);      // [204 px][24 ch]
    _Float16* tTl = (_Float16*)(smem + OFF_TTL);
    _Float16* zero16 = (_Float16*)(smem + OFF_Z16);
    _Float16* pH = (_Float16*)(smem + OFF_PH);        // [128 px][PK]
    _Float16* pL = (_Float16*)(smem + OFF_PL);

    const int n = blockIdx.x;            // image  (XCD-local: id%8 = n%8)
    const int strip = blockIdx.y;        // 0..7
    const int tid = threadIdx.x;
    const int r0 = strip * RB;
    const size_t nbase = (size_t)n * PIX * CPAD;
    const _Float16* Bh = Bnh + nbase;
    const _Float16* Bl = Bnl + nbase;

    const int wv = __builtin_amdgcn_readfirstlane(tid >> 6);  // 0..7
    const int lane = tid & 63;
    const int col = lane & 15;
    const int quad = lane >> 4;
    const int wm = wv >> 1;            // 0..3 : M-split (2 m-tiles each)
    const int wn = wv & 1;             // 0..1 : N-split (4 n-tiles each)

    // ---- phase A: reconstruct B ch0 (halo 2), prefetch Min + state chunks
    if (tid < 288) {
        int r = tid / 36, cq = tid % 36;
        int row = r0 - 2 + r, colg = cq - 2;
        float v = 0.f;
        if (row >= 0 && row < HW && colg >= 0 && colg < HW) {
            int gp = row * HW + colg;
            v = ((float)Bh[gp * CPAD] + (float)Bl[gp * CPAD]) * ISCL;
        }
        bch0[tid] = v;
    }
    unsigned char minb = 0;
    if (tid < TPX) {
        int tr = tid / 34, tc = tid % 34;
        int y = r0 - 1 + tr, xc = tc - 1;
        if (y >= 0 && y < HW && xc >= 0 && xc < HW)
            minb = Min[n * PIX + y * HW + xc];
    }
    half8 gh[2], gl[2];
    #pragma unroll
    for (int it = 0; it < 2; ++it) {
        int idx = tid + 512 * it;                 // 612 chunks of 8 channels
        gh[it] = (half8){}; gl[it] = (half8){};
        if (idx < TPX * 3) {
            int pxs = idx / 3, part = idx % 3;
            int tr = pxs / 34, tc = pxs % 34;
            int y = r0 - 1 + tr, xc = tc - 1;
            if (y >= 0 && y < HW && xc >= 0 && xc < HW) {
                int off = (y * HW + xc) * CPAD + part * 8;
                gh[it] = *(const half8*)(Bh + off);
                gl[it] = *(const half8*)(Bl + off);
            }
        }
    }
    if (tid < 8) zero16[tid] = (_Float16)0.f;
    __syncthreads();

    // ---- phase B: m4 = Min & (maxpool3(B ch0) > TH)
    int alive = 0;
    if (tid < TPX) {
        int tr = tid / 34, tc = tid % 34;
        float m = 0.f;
        if (minb) {
            float mx = -1e30f;
            #pragma unroll
            for (int dy = 0; dy < 3; ++dy)
                #pragma unroll
                for (int dx = 0; dx < 3; ++dx)
                    mx = fmaxf(mx, bch0[(tr + dy) * 36 + tc + dx]);
            if (mx > TH) m = 1.f;
        }
        m4[tid] = m;
        alive = (m != 0.f);
    }
    const int any = __syncthreads_or(alive);

    _Float16* BoH = Boh + nbase;
    _Float16* BoL = Bol + nbase;

    // ---- dead block: S' = u0 exactly, masks all zero
    if (!any) {
        if (tid < OPX)
            Mout[n * PIX + (r0 + (tid >> 5)) * HW + (tid & 31)] = 0;
        if (tid < OPX * 3) {
            int pl = tid / 3, pt = tid % 3;
            int gp = (r0 + (pl >> 5)) * HW + (pl & 31);
            *(half8*)(BoH + gp * CPAD + pt * 8) = *(const half8*)(u0h + pt * 8);
            *(half8*)(BoL + gp * CPAD + pt * 8) = *(const half8*)(u0l + pt * 8);
        }
        return;
    }

    // ---- phase C: tT = prefetched split-state * mask (exact); next pre-mask
    #pragma unroll
    for (int it = 0; it < 2; ++it) {
        int idx = tid + 512 * it;
        if (idx < TPX * 3) {
            int pxs = idx / 3, part = idx % 3;
            _Float16 mh = (_Float16)m4[pxs];
            *(half8*)&tTh[pxs * 24 + part * 8] = gh[it] * mh;
            *(half8*)&tTl[pxs * 24 + part * 8] = gl[it] * mh;
        }
    }
    if (tid < OPX) {
        int ry = tid >> 5, xx = tid & 31;
        float mx = -1e30f;
        #pragma unroll
        for (int dy = 0; dy < 3; ++dy)
            #pragma unroll
            for (int dx = 0; dx < 3; ++dx)
                mx = fmaxf(mx, bch0[(ry + dy + 1) * 36 + (xx + dx + 1)] *
                               m4[(ry + dy) * 34 + (xx + dx)]);
        Mout[n * PIX + (r0 + ry) * HW + xx] = (mx > TH) ? 1 : 0;
    }
    __syncthreads();

    // ---- per-(ks,quad) fragment offset in tT; invalid -> zero line
    int koff[NKS1];
    #pragma unroll
    for (int ks = 0; ks < NKS1; ++ks) {
        int k0 = ks * 32 + quad * 8;
        int q = k0 / 24, c0 = k0 - q * 24;
        int dy = q / 3, dx = q - dy * 3;
        koff[ks] = (q < 9) ? (dy * 34 + dx) * 24 + c0 : -1;
    }
    int pbase[4];
    #pragma unroll
    for (int j = 0; j < 4; ++j) {
        int px = (wn * 4 + j) * 16 + col;
        pbase[j] = ((px >> 5) * 34 + (px & 31)) * 24;
    }

    // ---- GEMM 1: perc/16 = Wp @ tT, 2m x 4n per wave (weights streamed)
    floatx4 acc1[2][4];
    #pragma unroll
    for (int i = 0; i < 2; ++i) {
        floatx4 b = *(const floatx4*)(bp + (wm * 2 + i) * 16 + quad * 4) * SCL;
        #pragma unroll
        for (int j = 0; j < 4; ++j) acc1[i][j] = b;
    }
    #pragma unroll
    for (int ks = 0; ks < NKS1; ++ks) {
        half8 Ah[2], Al[2];
        #pragma unroll
        for (int i = 0; i < 2; ++i) {
            int mt = wm * 2 + i;
            Ah[i] = *(const half8*)(WpRh + ((mt * 7 + ks) * 64 + lane) * 8);
            Al[i] = *(const half8*)(WpRl + ((mt * 7 + ks) * 64 + lane) * 8);
        }
        half8 bh[4], bl[4];
        #pragma unroll
        for (int j = 0; j < 4; ++j) {
            const _Float16* sh = (koff[ks] >= 0) ? (tTh + pbase[j] + koff[ks]) : zero16;
            const _Float16* sl = (koff[ks] >= 0) ? (tTl + pbase[j] + koff[ks]) : zero16;
            bh[j] = *(const half8*)sh;
            bl[j] = *(const half8*)sl;
        }
        #pragma unroll
        for (int i = 0; i < 2; ++i)
            #pragma unroll
            for (int j = 0; j < 4; ++j) {
                acc1[i][j] = __builtin_amdgcn_mfma_f32_16x16x32_f16(Ah[i], bh[j], acc1[i][j], 0, 0, 0);
                acc1[i][j] = __builtin_amdgcn_mfma_f32_16x16x32_f16(Ah[i], bl[j], acc1[i][j], 0, 0, 0);
                acc1[i][j] = __builtin_amdgcn_mfma_f32_16x16x32_f16(Al[i], bh[j], acc1[i][j], 0, 0, 0);
            }
    }
    #pragma unroll
    for (int i = 0; i < 2; ++i)
        #pragma unroll
        for (int j = 0; j < 4; ++j) {
            const int px = (wn * 4 + j) * 16 + col;
            const int mb = (wm * 2 + i) * 16 + quad * 4;
            _Float16 h[4], l[4];
            #pragma unroll
            for (int r = 0; r < 4; ++r) {
                h[r] = (_Float16)acc1[i][j][r];
                l[r] = (_Float16)(acc1[i][j][r] - (float)h[r]);
            }
            *(half4v*)&pH[px * PK + mb] = (half4v){h[0], h[1], h[2], h[3]};
            *(half4v*)&pL[px * PK + mb] = (half4v){l[0], l[1], l[2], l[3]};
        }
    __syncthreads();

    // ---- GEMM 2: hid/16 = relu(W1 @ perc + b1)/16, 2m x 4n per wave
    floatx4 acc2[2][4];
    #pragma unroll
    for (int i = 0; i < 2; ++i) {
        floatx4 b = *(const floatx4*)(b1 + (wm * 2 + i) * 16 + quad * 4) * SCL;
        #pragma unroll
        for (int j = 0; j < 4; ++j) acc2[i][j] = b;
    }
    #pragma unroll
    for (int ks = 0; ks < 4; ++ks) {
        half8 Ah[2], Al[2];
        #pragma unroll
        for (int i = 0; i < 2; ++i) {
            int mt = wm * 2 + i;
            Ah[i] = *(const half8*)(W1Rh + ((mt * 4 + ks) * 64 + lane) * 8);
            Al[i] = *(const half8*)(W1Rl + ((mt * 4 + ks) * 64 + lane) * 8);
        }
        half8 bh[4], bl[4];
        #pragma unroll
        for (int j = 0; j < 4; ++j) {
            const int px = (wn * 4 + j) * 16 + col;
            bh[j] = *(const half8*)&pH[px * PK + ks * 32 + quad * 8];
            bl[j] = *(const half8*)&pL[px * PK + ks * 32 + quad * 8];
        }
        #pragma unroll
        for (int i = 0; i < 2; ++i)
            #pragma unroll
            for (int j = 0; j < 4; ++j) {
                acc2[i][j] = __builtin_amdgcn_mfma_f32_16x16x32_f16(Ah[i], bh[j], acc2[i][j], 0, 0, 0);
                acc2[i][j] = __builtin_amdgcn_mfma_f32_16x16x32_f16(Ah[i], bl[j], acc2[i][j], 0, 0, 0);
                acc2[i][j] = __builtin_amdgcn_mfma_f32_16x16x32_f16(Al[i], bh[j], acc2[i][j], 0, 0, 0);
            }
    }
    __syncthreads();                        // all perc reads complete
    #pragma unroll
    for (int i = 0; i < 2; ++i)
        #pragma unroll
        for (int j = 0; j < 4; ++j) {
            const int px = (wn * 4 + j) * 16 + col;
            const int mb = (wm * 2 + i) * 16 + quad * 4;
            _Float16 h[4], l[4];
            #pragma unroll
            for (int r = 0; r < 4; ++r) {
                float hv = fmaxf(acc2[i][j][r], 0.f);
                h[r] = (_Float16)hv;
                l[r] = (_Float16)(hv - (float)h[r]);
            }
            *(half4v*)&pH[px * PK + mb] = (half4v){h[0], h[1], h[2], h[3]};
            *(half4v*)&pL[px * PK + mb] = (half4v){l[0], l[1], l[2], l[3]};
        }
    __syncthreads();

    // ---- GEMM 3: wave = (mt3 = wv&1, n-tiles {2*(wv>>1), 2*(wv>>1)+1})
    const int mt3 = wv & 1, ntb = (wv >> 1) * 2;
    floatx4 accU[2];
    accU[0] = (floatx4){0.f, 0.f, 0.f, 0.f};
    accU[1] = (floatx4){0.f, 0.f, 0.f, 0.f};
    #pragma unroll
    for (int ks = 0; ks < 4; ++ks) {
        half8 ah = *(const half8*)(W2Rh + ((mt3 * 4 + ks) * 64 + lane) * 8);
        half8 al = *(const half8*)(W2Rl + ((mt3 * 4 + ks) * 64 + lane) * 8);
        #pragma unroll
        for (int j = 0; j < 2; ++j) {
            const int pxU = (ntb + j) * 16 + col;
            half8 bh = *(const half8*)&pH[pxU * PK + ks * 32 + quad * 8];
            half8 bl = *(const half8*)&pL[pxU * PK + ks * 32 + quad * 8];
            accU[j] = __builtin_amdgcn_mfma_f32_16x16x32_f16(ah, bh, accU[j], 0, 0, 0);
            accU[j] = __builtin_amdgcn_mfma_f32_16x16x32_f16(ah, bl, accU[j], 0, 0, 0);
            accU[j] = __builtin_amdgcn_mfma_f32_16x16x32_f16(al, bh, accU[j], 0, 0, 0);
        }
    }
    const int m0 = mt3 * 16 + quad * 4;
    #pragma unroll
    for (int j = 0; j < 2; ++j) {
        const int pxU = (ntb + j) * 16 + col;
        const int py = pxU >> 5, pxx = pxU & 31;
        const float mval = m4[(py + 1) * 34 + pxx + 1];
        const int gp = (r0 + py) * HW + pxx;
        if (m0 < ST) {                              // channels m0..m0+3 (<20)
            half4v oh4 = *(const half4v*)(Bh + gp * CPAD + m0);
            half4v ol4 = *(const half4v*)(Bl + gp * CPAD + m0);
            floatx4 b2v = *(const floatx4*)(b2 + m0);
            _Float16 nh[4], nl[4];
            #pragma unroll
            for (int r = 0; r < 4; ++r) {
                float sOld = ((float)oh4[r] + (float)ol4[r]) * ISCL;
                float out = sOld * mval + ISCL * accU[j][r] + b2v[r];
                float os = out * SCL;
                nh[r] = (_Float16)os;
                nl[r] = (_Float16)(os - (float)nh[r]);
            }
            *(half4v*)(BoH + gp * CPAD + m0) = (half4v){nh[0], nh[1], nh[2], nh[3]};
            *(half4v*)(BoL + gp * CPAD + m0) = (half4v){nl[0], nl[1], nl[2], nl[3]};
        } else if (m0 == 20) {                      // zero the channel pad
            *(half4v*)(BoH + gp * CPAD + 20) = (half4v){0, 0, 0, 0};
            *(half4v*)(BoL + gp * CPAD + 20) = (half4v){0, 0, 0, 0};
        }
    }
}

// ---------------------------------------------------------------------------
// finalize: out ch0 = recon(B ch0) * (M & postmask(recon B ch0))
__global__ __launch_bounds__(256) void finalize_kernel(
    const _Float16* __restrict__ Bh, const _Float16* __restrict__ Bl,
    const unsigned char* __restrict__ M, float* __restrict__ out)
{
    const int n = blockIdx.y;
    const int p = blockIdx.x * 256 + threadIdx.x;
    const int y = p >> 5, x = p & 31;
    const size_t nbase = (size_t)n * PIX * CPAD;
    float m = 0.f;
    if (M[n * PIX + p]) {
        float mx = -1e30f;
        for (int dy = -1; dy <= 1; ++dy) {
            int yy = y + dy; if (yy < 0 || yy >= HW) continue;
            for (int dx = -1; dx <= 1; ++dx) {
                int xx = x + dx; if (xx < 0 || xx >= HW) continue;
                int gp = yy * HW + xx;
                float v = ((float)Bh[nbase + gp * CPAD] +
                           (float)Bl[nbase + gp * CPAD]) * ISCL;
                mx = fmaxf(mx, v);
            }
        }
        if (mx > TH) m = 1.f;
    }
    float s0 = ((float)Bh[nbase + p * CPAD] + (float)Bl[nbase + p * CPAD]) * ISCL;
    out[n * PIX + p] = s0 * m;
}

// ---------------------------------------------------------------------------
extern "C" void kernel_launch(void* const* d_in, const int* in_sizes, int n_in,
                              void* d_out, int out_size, void* d_ws, size_t ws_size,
                              hipStream_t stream)
{
    const float* z       = (const float*)d_in[0];
    const float* w_init1 = (const float*)d_in[1];
    const float* b_init1 = (const float*)d_in[2];
    const float* w_init2 = (const float*)d_in[3];
    const float* b_init2 = (const float*)d_in[4];
    const float* w_perc  = (const float*)d_in[5];
    const float* b_perc  = (const float*)d_in[6];
    const float* w_up1   = (const float*)d_in[7];
    const float* b_up1   = (const float*)d_in[8];
    const float* w_up2   = (const float*)d_in[9];
    const float* b_up2   = (const float*)d_in[10];

    const size_t SB = (size_t)NB * PIX * CPAD;     // 786432 halfs per array
    _Float16* B0h = (_Float16*)d_ws;
    _Float16* B0l = B0h + SB;
    _Float16* B1h = B0l + SB;
    _Float16* B1l = B1h + SB;
    unsigned char* M0 = (unsigned char*)(B1l + SB);
    unsigned char* M1 = M0 + NB * PIX;
    _Float16* WpRh = (_Float16*)(M1 + NB * PIX);
    _Float16* WpRl = WpRh + 28672;
    _Float16* W1Rh = WpRl + 28672;
    _Float16* W1Rl = W1Rh + 16384;
    _Float16* W2Rh = W1Rl + 16384;
    _Float16* W2Rl = W2Rh + 4096;
    _Float16* u0h  = W2Rl + 4096;
    _Float16* u0l  = u0h + CPAD;

    // opt-in to >64 KB dynamic LDS for the step kernel (idempotent)
    hipFuncSetAttribute((const void*)ca_step_kernel,
                        hipFuncAttributeMaxDynamicSharedMemorySize, LDS_BYTES);

    repack_kernel<<<192, 256, 0, stream>>>(w_perc, w_up1, w_up2,
                                           WpRh, WpRl, W1Rh, W1Rl, W2Rh, W2Rl);
    u0_kernel<<<1, 128, 0, stream>>>(b_perc, w_up1, b_up1, w_up2, b_up2, u0h, u0l);
    hipMemsetAsync(B0h, 0, SB * 2 * sizeof(_Float16), stream);  // B0h + B0l
    init_state_kernel<<<NB, 64, 0, stream>>>(z, w_init1, b_init1, w_init2,
                                             b_init2, B0h, B0l, M0);

    for (int s = 0; s < STEPS; ++s) {
        const _Float16* bih = (s & 1) ? B1h : B0h;
        const _Float16* bil = (s & 1) ? B1l : B0l;
        _Float16* boh       = (s & 1) ? B0h : B1h;
        _Float16* bol       = (s & 1) ? B0l : B1l;
        const unsigned char* mi = (s & 1) ? M1 : M0;
        unsigned char* mo       = (s & 1) ? M0 : M1;
        // grid (image, strip8): linear id = n + 32*strip -> id%8 = n%8 ->
        // each image's 8 strips co-resident on one XCD (halo stays in L2)
        ca_step_kernel<<<dim3(NB, 8), 512, LDS_BYTES, stream>>>(
            bih, bil, mi, boh, bol, mo, WpRh, WpRl, b_perc,
            W1Rh, W1Rl, b_up1, W2Rh, W2Rl, b_up2, u0h, u0l);
    }
    // 64 steps (even) -> final state in (B0, M0)
    finalize_kernel<<<dim3(4, NB), 256, 0, stream>>>(B0h, B0l, M0, (float*)d_out);
}

// Round 15
// 664.866 us; speedup vs baseline: 1.3983x; 1.3983x over previous
//
#include <hip/hip_runtime.h>

#define NB 32
#define NZ 100
#define ST 20
#define HID 128
#define HW 32
#define PIX 1024
#define STEPS 64
#define TH 0.1f
#define SCL 0.0625f     // 1/16 stored-value scaling (power of 2)
#define ISCL 16.0f
#define CPAD 24         // channel stride in split-state storage (20 + 4 pad)

typedef _Float16 half8  __attribute__((ext_vector_type(8)));
typedef _Float16 half4v __attribute__((ext_vector_type(4)));
typedef float    floatx4 __attribute__((ext_vector_type(4)));

// perceive GEMM K layout: k = q*24 + c  (q=dy*3+dx in 0..8, c in 0..23, pad from 20)
#define NKS1 7
#define PK 136          // perc/hid LDS row stride

// ---------------------------------------------------------------------------
// init: init_hidden scattered to center, written as split fp16 (value/16).
__global__ __launch_bounds__(64) void init_state_kernel(
    const float* __restrict__ z, const float* __restrict__ w1,
    const float* __restrict__ b1, const float* __restrict__ w2,
    const float* __restrict__ b2, _Float16* __restrict__ Bh,
    _Float16* __restrict__ Bl, unsigned char* __restrict__ M)
{
    __shared__ float zs[NZ];
    __shared__ float h1[50];
    const int n = blockIdx.x;
    const int t = threadIdx.x;
    for (int i = t; i < NZ; i += 64) zs[i] = z[n * NZ + i];
    __syncthreads();
    if (t < 50) {
        float a = b1[t];
        for (int i = 0; i < NZ; ++i) a += w1[t * NZ + i] * zs[i];
        h1[t] = fmaxf(a, 0.f);
    }
    __syncthreads();
    const int gp = 16 * HW + 16;                 // center pixel
    if (t < ST - 1) {
        float a = b2[t];
        for (int j = 0; j < 50; ++j) a += w2[t * 50 + j] * h1[j];
        float vs = a * SCL;
        _Float16 hi = (_Float16)vs;
        Bh[(size_t)n * PIX * CPAD + gp * CPAD + (t + 1)] = hi;
        Bl[(size_t)n * PIX * CPAD + gp * CPAD + (t + 1)] = (_Float16)(vs - (float)hi);
    }
    if (t == 63) {
        Bh[(size_t)n * PIX * CPAD + gp * CPAD] = (_Float16)(0.5f * SCL);  // exact
        Bl[(size_t)n * PIX * CPAD + gp * CPAD] = (_Float16)0.f;
    }
    for (int i = t; i < PIX; i += 64) M[n * PIX + i] = 1;
}

// ---------------------------------------------------------------------------
// Repack weights into MFMA A-fragment order as fp16 hi/lo pairs.
__global__ __launch_bounds__(256) void repack_kernel(
    const float* __restrict__ Wp, const float* __restrict__ W1,
    const float* __restrict__ W2,
    _Float16* __restrict__ WpRh, _Float16* __restrict__ WpRl,
    _Float16* __restrict__ W1Rh, _Float16* __restrict__ W1Rl,
    _Float16* __restrict__ W2Rh, _Float16* __restrict__ W2Rl)
{
    int e = blockIdx.x * 256 + threadIdx.x;
    if (e < 28672) {
        int j = e & 7, lane = (e >> 3) & 63, t2 = e >> 9;   // t2 = w*7+ks
        int ks = t2 % 7, w = t2 / 7;
        int m = w * 16 + (lane & 15);
        int k = ks * 32 + ((lane >> 4) << 3) + j;
        int q = k / 24, c = k - q * 24;
        float v = (q < 9 && c < ST) ? Wp[m * 180 + c * 9 + q] : 0.f;
        _Float16 hi = (_Float16)v;
        WpRh[e] = hi; WpRl[e] = (_Float16)(v - (float)hi);
    } else if (e < 45056) {
        int e2 = e - 28672;
        int j = e2 & 7, lane = (e2 >> 3) & 63, t2 = e2 >> 9; // t2 = w*4+ks
        int ks = t2 & 3, w = t2 >> 2;
        int m = w * 16 + (lane & 15);
        int k = ks * 32 + ((lane >> 4) << 3) + j;
        float v = W1[m * 128 + k];
        _Float16 hi = (_Float16)v;
        W1Rh[e2] = hi; W1Rl[e2] = (_Float16)(v - (float)hi);
    } else if (e < 49152) {
        int e3 = e - 45056;
        int j = e3 & 7, lane = (e3 >> 3) & 63, t2 = e3 >> 9; // t2 = mt*4+ks
        int ks = t2 & 3, mt = t2 >> 2;
        int m = mt * 16 + (lane & 15);
        int k = ks * 32 + ((lane >> 4) << 3) + j;
        float v = (m < ST) ? W2[m * 128 + k] : 0.f;
        _Float16 hi = (_Float16)v;
        W2Rh[e3] = hi; W2Rl[e3] = (_Float16)(v - (float)hi);
    }
}

// ---------------------------------------------------------------------------
// u0 = b2 + W2 @ relu(b1 + W1 @ bp): exact S' of a dead region (split fp16 /16).
__global__ __launch_bounds__(128) void u0_kernel(
    const float* __restrict__ bp, const float* __restrict__ W1,
    const float* __restrict__ b1, const float* __restrict__ W2,
    const float* __restrict__ b2,
    _Float16* __restrict__ u0h, _Float16* __restrict__ u0l)
{
    __shared__ float h[128];
    const int t = threadIdx.x;
    float a = b1[t];
    for (int i = 0; i < HID; ++i) a += W1[t * HID + i] * bp[i];
    h[t] = fmaxf(a, 0.f);
    __syncthreads();
    if (t < CPAD) {
        float u = 0.f;
        if (t < ST) {
            u = b2[t];
            for (int j = 0; j < HID; ++j) u += W2[t * HID + j] * h[j];
        }
        float us = u * SCL;
        _Float16 hi = (_Float16)us;
        u0h[t] = hi;
        u0l[t] = (_Float16)(us - (float)hi);
    }
}

// ---------------------------------------------------------------------------
// Fused CA step (split-fp16 MFMA, 4Mx2N wave tiling, split-state storage).
// R15 = R12 verbatim (the 666 us config): XCD-local grid swizzle
// (blockIdx.x = image -> linear id%8 = n%8 -> all 16 strips of an image on
// ONE XCD; halo exchange stays in per-XCD L2), 2-row strips, 512 thr,
// 2 blocks/CU. Measured optimum of the tile-space (R6/R9/R10/R13/R14 all
// regressed on every neighboring axis).
__global__ __launch_bounds__(512, 4) void ca_step_kernel(
    const _Float16* __restrict__ Bnh, const _Float16* __restrict__ Bnl,
    const unsigned char* __restrict__ Min,
    _Float16* __restrict__ Boh, _Float16* __restrict__ Bol,
    unsigned char* __restrict__ Mout,
    const _Float16* __restrict__ WpRh, const _Float16* __restrict__ WpRl,
    const float* __restrict__ bp,
    const _Float16* __restrict__ W1Rh, const _Float16* __restrict__ W1Rl,
    const float* __restrict__ b1,
    const _Float16* __restrict__ W2Rh, const _Float16* __restrict__ W2Rl,
    const float* __restrict__ b2,
    const _Float16* __restrict__ u0h, const _Float16* __restrict__ u0l)
{
    __shared__ float bch0[216];
    __shared__ float m4[136];
    __shared__ __align__(16) _Float16 tTh[4 * 34 * 24];
    __shared__ __align__(16) _Float16 tTl[4 * 34 * 24];
    __shared__ __align__(16) _Float16 zero16[8];
    __shared__ __align__(16) _Float16 pH[64 * PK];
    __shared__ __align__(16) _Float16 pL[64 * PK];

    const int n = blockIdx.x;            // image  (XCD-local: id%8 = n%8)
    const int strip = blockIdx.y;        // strip
    const int tid = threadIdx.x;
    const int r0 = strip * 2;
    const size_t nbase = (size_t)n * PIX * CPAD;
    const _Float16* Bh = Bnh + nbase;
    const _Float16* Bl = Bnl + nbase;

    const int wv = __builtin_amdgcn_readfirstlane(tid >> 6);
    const int lane = tid & 63;
    const int col = lane & 15;
    const int quad = lane >> 4;
    const int wm = wv >> 1;            // 0..3 : M-split (2 m-tiles each)
    const int wn = wv & 1;             // 0..1 : N-split (2 n-tiles each)

    // ---- phase A: reconstruct B ch0 (halo 2), prefetch Min + state chunks
    if (tid < 216) {
        int r = tid / 36, cq = tid % 36;
        int row = r0 - 2 + r, colg = cq - 2;
        float v = 0.f;
        if (row >= 0 && row < HW && colg >= 0 && colg < HW) {
            int gp = row * HW + colg;
            v = ((float)Bh[gp * CPAD] + (float)Bl[gp * CPAD]) * ISCL;
        }
        bch0[tid] = v;
    }
    unsigned char minb = 0;
    if (tid < 136) {
        int tr = tid / 34, tc = tid % 34;
        int y = r0 - 1 + tr, xc = tc - 1;
        if (y >= 0 && y < HW && xc >= 0 && xc < HW)
            minb = Min[n * PIX + y * HW + xc];
    }
    const int px_s = tid / 3, part = tid % 3;    // 408 chunks of 8 channels
    half8 gh = {}, gl = {};
    if (tid < 408) {
        int tr = px_s / 34, tc = px_s % 34;
        int y = r0 - 1 + tr, xc = tc - 1;
        if (y >= 0 && y < HW && xc >= 0 && xc < HW) {
            int off = (y * HW + xc) * CPAD + part * 8;
            gh = *(const half8*)(Bh + off);
            gl = *(const half8*)(Bl + off);
        }
    }
    if (tid < 8) zero16[tid] = (_Float16)0.f;
    __syncthreads();

    // ---- phase B: m4 = Min & (maxpool3(B ch0) > TH)
    int alive = 0;
    if (tid < 136) {
        int tr = tid / 34, tc = tid % 34;
        float m = 0.f;
        if (minb) {
            float mx = -1e30f;
            #pragma unroll
            for (int dy = 0; dy < 3; ++dy)
                #pragma unroll
                for (int dx = 0; dx < 3; ++dx)
                    mx = fmaxf(mx, bch0[(tr + dy) * 36 + tc + dx]);
            if (mx > TH) m = 1.f;
        }
        m4[tid] = m;
        alive = (m != 0.f);
    }
    const int any = __syncthreads_or(alive);

    _Float16* BoH = Boh + nbase;
    _Float16* BoL = Bol + nbase;

    // ---- dead block: S' = u0 exactly, masks all zero
    if (!any) {
        if (tid < 64)
            Mout[n * PIX + (r0 + (tid >> 5)) * HW + (tid & 31)] = 0;
        if (tid < 192) {
            int pl = tid / 3, pt = tid % 3;
            int gp = (r0 + (pl >> 5)) * HW + (pl & 31);
            *(half8*)(BoH + gp * CPAD + pt * 8) = *(const half8*)(u0h + pt * 8);
            *(half8*)(BoL + gp * CPAD + pt * 8) = *(const half8*)(u0l + pt * 8);
        }
        return;
    }

    // ---- phase C: tT = prefetched split-state * mask (exact); next pre-mask
    if (tid < 408) {
        _Float16 mh = (_Float16)m4[px_s];
        *(half8*)&tTh[px_s * 24 + part * 8] = gh * mh;
        *(half8*)&tTl[px_s * 24 + part * 8] = gl * mh;
    }
    if (tid < 64) {
        int ry = lane >> 5, xx = lane & 31;
        float mx = -1e30f;
        #pragma unroll
        for (int dy = 0; dy < 3; ++dy)
            #pragma unroll
            for (int dx = 0; dx < 3; ++dx)
                mx = fmaxf(mx, bch0[(ry + dy + 1) * 36 + (xx + dx + 1)] *
                               m4[(ry + dy) * 34 + (xx + dx)]);
        Mout[n * PIX + (r0 + ry) * HW + xx] = (mx > TH) ? 1 : 0;
    }
    __syncthreads();

    // ---- per-(ks,quad) fragment offset in tT; invalid -> zero line
    int koff[NKS1];
    #pragma unroll
    for (int ks = 0; ks < NKS1; ++ks) {
        int k0 = ks * 32 + quad * 8;
        int q = k0 / 24, c0 = k0 - q * 24;
        int dy = q / 3, dx = q - dy * 3;
        koff[ks] = (q < 9) ? (dy * 34 + dx) * 24 + c0 : -1;
    }
    int pbase[2];
    #pragma unroll
    for (int j = 0; j < 2; ++j) {
        int px = (wn * 2 + j) * 16 + col;
        pbase[j] = ((px >> 5) * 34 + (px & 31)) * 24;
    }

    // ---- GEMM 1: perc/16 = Wp @ tT, 2m x 2n per wave (weights streamed)
    floatx4 acc1[2][2];
    #pragma unroll
    for (int i = 0; i < 2; ++i) {
        floatx4 b = *(const floatx4*)(bp + (wm * 2 + i) * 16 + quad * 4) * SCL;
        acc1[i][0] = b; acc1[i][1] = b;
    }
    #pragma unroll
    for (int ks = 0; ks < NKS1; ++ks) {
        half8 Ah[2], Al[2];
        #pragma unroll
        for (int i = 0; i < 2; ++i) {
            int mt = wm * 2 + i;
            Ah[i] = *(const half8*)(WpRh + ((mt * 7 + ks) * 64 + lane) * 8);
            Al[i] = *(const half8*)(WpRl + ((mt * 7 + ks) * 64 + lane) * 8);
        }
        half8 bh[2], bl[2];
        #pragma unroll
        for (int j = 0; j < 2; ++j) {
            const _Float16* sh = (koff[ks] >= 0) ? (tTh + pbase[j] + koff[ks]) : zero16;
            const _Float16* sl = (koff[ks] >= 0) ? (tTl + pbase[j] + koff[ks]) : zero16;
            bh[j] = *(const half8*)sh;
            bl[j] = *(const half8*)sl;
        }
        #pragma unroll
        for (int i = 0; i < 2; ++i)
            #pragma unroll
            for (int j = 0; j < 2; ++j) {
                acc1[i][j] = __builtin_amdgcn_mfma_f32_16x16x32_f16(Ah[i], bh[j], acc1[i][j], 0, 0, 0);
                acc1[i][j] = __builtin_amdgcn_mfma_f32_16x16x32_f16(Ah[i], bl[j], acc1[i][j], 0, 0, 0);
                acc1[i][j] = __builtin_amdgcn_mfma_f32_16x16x32_f16(Al[i], bh[j], acc1[i][j], 0, 0, 0);
            }
    }
    #pragma unroll
    for (int i = 0; i < 2; ++i)
        #pragma unroll
        for (int j = 0; j < 2; ++j) {
            const int px = (wn * 2 + j) * 16 + col;
            const int mb = (wm * 2 + i) * 16 + quad * 4;
            _Float16 h[4], l[4];
            #pragma unroll
            for (int r = 0; r < 4; ++r) {
                h[r] = (_Float16)acc1[i][j][r];
                l[r] = (_Float16)(acc1[i][j][r] - (float)h[r]);
            }
            *(half4v*)&pH[px * PK + mb] = (half4v){h[0], h[1], h[2], h[3]};
            *(half4v*)&pL[px * PK + mb] = (half4v){l[0], l[1], l[2], l[3]};
        }
    __syncthreads();

    // ---- GEMM 2: hid/16 = relu(W1 @ perc + b1)/16
    floatx4 acc2[2][2];
    #pragma unroll
    for (int i = 0; i < 2; ++i) {
        floatx4 b = *(const floatx4*)(b1 + (wm * 2 + i) * 16 + quad * 4) * SCL;
        acc2[i][0] = b; acc2[i][1] = b;
    }
    #pragma unroll
    for (int ks = 0; ks < 4; ++ks) {
        half8 Ah[2], Al[2];
        #pragma unroll
        for (int i = 0; i < 2; ++i) {
            int mt = wm * 2 + i;
            Ah[i] = *(const half8*)(W1Rh + ((mt * 4 + ks) * 64 + lane) * 8);
            Al[i] = *(const half8*)(W1Rl + ((mt * 4 + ks) * 64 + lane) * 8);
        }
        half8 bh[2], bl[2];
        #pragma unroll
        for (int j = 0; j < 2; ++j) {
            const int px = (wn * 2 + j) * 16 + col;
            bh[j] = *(const half8*)&pH[px * PK + ks * 32 + quad * 8];
            bl[j] = *(const half8*)&pL[px * PK + ks * 32 + quad * 8];
        }
        #pragma unroll
        for (int i = 0; i < 2; ++i)
            #pragma unroll
            for (int j = 0; j < 2; ++j) {
                acc2[i][j] = __builtin_amdgcn_mfma_f32_16x16x32_f16(Ah[i], bh[j], acc2[i][j], 0, 0, 0);
                acc2[i][j] = __builtin_amdgcn_mfma_f32_16x16x32_f16(Ah[i], bl[j], acc2[i][j], 0, 0, 0);
                acc2[i][j] = __builtin_amdgcn_mfma_f32_16x16x32_f16(Al[i], bh[j], acc2[i][j], 0, 0, 0);
            }
    }
    __syncthreads();                        // all perc reads complete
    #pragma unroll
    for (int i = 0; i < 2; ++i)
        #pragma unroll
        for (int j = 0; j < 2; ++j) {
            const int px = (wn * 2 + j) * 16 + col;
            const int mb = (wm * 2 + i) * 16 + quad * 4;
            _Float16 h[4], l[4];
            #pragma unroll
            for (int r = 0; r < 4; ++r) {
                float hv = fmaxf(acc2[i][j][r], 0.f);
                h[r] = (_Float16)hv;
                l[r] = (_Float16)(hv - (float)h[r]);
            }
            *(half4v*)&pH[px * PK + mb] = (half4v){h[0], h[1], h[2], h[3]};
            *(half4v*)&pL[px * PK + mb] = (half4v){l[0], l[1], l[2], l[3]};
        }
    __syncthreads();

    // ---- GEMM 3 (dedup): wave = (mt = wv&1, nt = wv>>1)
    const int mt3 = wv & 1, ntU = wv >> 1;
    floatx4 accU = {0.f, 0.f, 0.f, 0.f};
    const int pxU = ntU * 16 + col;
    #pragma unroll
    for (int ks = 0; ks < 4; ++ks) {
        half8 ah = *(const half8*)(W2Rh + ((mt3 * 4 + ks) * 64 + lane) * 8);
        half8 al = *(const half8*)(W2Rl + ((mt3 * 4 + ks) * 64 + lane) * 8);
        half8 bh = *(const half8*)&pH[pxU * PK + ks * 32 + quad * 8];
        half8 bl = *(const half8*)&pL[pxU * PK + ks * 32 + quad * 8];
        accU = __builtin_amdgcn_mfma_f32_16x16x32_f16(ah, bh, accU, 0, 0, 0);
        accU = __builtin_amdgcn_mfma_f32_16x16x32_f16(ah, bl, accU, 0, 0, 0);
        accU = __builtin_amdgcn_mfma_f32_16x16x32_f16(al, bh, accU, 0, 0, 0);
    }
    const int py = pxU >> 5, pxx = pxU & 31;
    const float mval = m4[(py + 1) * 34 + pxx + 1];
    const int gp = (r0 + py) * HW + pxx;
    const int m0 = mt3 * 16 + quad * 4;
    if (m0 < ST) {                                  // channels m0..m0+3 (<20)
        half4v oh4 = *(const half4v*)(Bh + gp * CPAD + m0);
        half4v ol4 = *(const half4v*)(Bl + gp * CPAD + m0);
        floatx4 b2v = *(const floatx4*)(b2 + m0);
        _Float16 nh[4], nl[4];
        #pragma unroll
        for (int r = 0; r < 4; ++r) {
            float sOld = ((float)oh4[r] + (float)ol4[r]) * ISCL;
            float out = sOld * mval + ISCL * accU[r] + b2v[r];
            float os = out * SCL;
            nh[r] = (_Float16)os;
            nl[r] = (_Float16)(os - (float)nh[r]);
        }
        *(half4v*)(BoH + gp * CPAD + m0) = (half4v){nh[0], nh[1], nh[2], nh[3]};
        *(half4v*)(BoL + gp * CPAD + m0) = (half4v){nl[0], nl[1], nl[2], nl[3]};
    } else if (m0 == 20) {                          // zero the channel pad
        *(half4v*)(BoH + gp * CPAD + 20) = (half4v){0, 0, 0, 0};
        *(half4v*)(BoL + gp * CPAD + 20) = (half4v){0, 0, 0, 0};
    }
}

// ---------------------------------------------------------------------------
// finalize: out ch0 = recon(B ch0) * (M & postmask(recon B ch0))
__global__ __launch_bounds__(256) void finalize_kernel(
    const _Float16* __restrict__ Bh, const _Float16* __restrict__ Bl,
    const unsigned char* __restrict__ M, float* __restrict__ out)
{
    const int n = blockIdx.y;
    const int p = blockIdx.x * 256 + threadIdx.x;
    const int y = p >> 5, x = p & 31;
    const size_t nbase = (size_t)n * PIX * CPAD;
    float m = 0.f;
    if (M[n * PIX + p]) {
        float mx = -1e30f;
        for (int dy = -1; dy <= 1; ++dy) {
            int yy = y + dy; if (yy < 0 || yy >= HW) continue;
            for (int dx = -1; dx <= 1; ++dx) {
                int xx = x + dx; if (xx < 0 || xx >= HW) continue;
                int gp = yy * HW + xx;
                float v = ((float)Bh[nbase + gp * CPAD] +
                           (float)Bl[nbase + gp * CPAD]) * ISCL;
                mx = fmaxf(mx, v);
            }
        }
        if (mx > TH) m = 1.f;
    }
    float s0 = ((float)Bh[nbase + p * CPAD] + (float)Bl[nbase + p * CPAD]) * ISCL;
    out[n * PIX + p] = s0 * m;
}

// ---------------------------------------------------------------------------
extern "C" void kernel_launch(void* const* d_in, const int* in_sizes, int n_in,
                              void* d_out, int out_size, void* d_ws, size_t ws_size,
                              hipStream_t stream)
{
    const float* z       = (const float*)d_in[0];
    const float* w_init1 = (const float*)d_in[1];
    const float* b_init1 = (const float*)d_in[2];
    const float* w_init2 = (const float*)d_in[3];
    const float* b_init2 = (const float*)d_in[4];
    const float* w_perc  = (const float*)d_in[5];
    const float* b_perc  = (const float*)d_in[6];
    const float* w_up1   = (const float*)d_in[7];
    const float* b_up1   = (const float*)d_in[8];
    const float* w_up2   = (const float*)d_in[9];
    const float* b_up2   = (const float*)d_in[10];

    const size_t SB = (size_t)NB * PIX * CPAD;     // 786432 halfs per array
    _Float16* B0h = (_Float16*)d_ws;
    _Float16* B0l = B0h + SB;
    _Float16* B1h = B0l + SB;
    _Float16* B1l = B1h + SB;
    unsigned char* M0 = (unsigned char*)(B1l + SB);
    unsigned char* M1 = M0 + NB * PIX;
    _Float16* WpRh = (_Float16*)(M1 + NB * PIX);
    _Float16* WpRl = WpRh + 28672;
    _Float16* W1Rh = WpRl + 28672;
    _Float16* W1Rl = W1Rh + 16384;
    _Float16* W2Rh = W1Rl + 16384;
    _Float16* W2Rl = W2Rh + 4096;
    _Float16* u0h  = W2Rl + 4096;
    _Float16* u0l  = u0h + CPAD;

    repack_kernel<<<192, 256, 0, stream>>>(w_perc, w_up1, w_up2,
                                           WpRh, WpRl, W1Rh, W1Rl, W2Rh, W2Rl);
    u0_kernel<<<1, 128, 0, stream>>>(b_perc, w_up1, b_up1, w_up2, b_up2, u0h, u0l);
    hipMemsetAsync(B0h, 0, SB * 2 * sizeof(_Float16), stream);  // B0h + B0l
    init_state_kernel<<<NB, 64, 0, stream>>>(z, w_init1, b_init1, w_init2,
                                             b_init2, B0h, B0l, M0);

    for (int s = 0; s < STEPS; ++s) {
        const _Float16* bih = (s & 1) ? B1h : B0h;
        const _Float16* bil = (s & 1) ? B1l : B0l;
        _Float16* boh       = (s & 1) ? B0h : B1h;
        _Float16* bol       = (s & 1) ? B0l : B1l;
        const unsigned char* mi = (s & 1) ? M1 : M0;
        unsigned char* mo       = (s & 1) ? M0 : M1;
        // grid (image, strip): linear id = n + 32*strip -> id%8 = n%8 ->
        // each image's 16 strips co-resident on one XCD (halo stays in L2)
        ca_step_kernel<<<dim3(NB, 16), 512, 0, stream>>>(
            bih, bil, mi, boh, bol, mo, WpRh, WpRl, b_perc,
            W1Rh, W1Rl, b_up1, W2Rh, W2Rl, b_up2, u0h, u0l);
    }
    // 64 steps (even) -> final state in (B0, M0)
    finalize_kernel<<<dim3(4, NB), 256, 0, stream>>>(B0h, B0l, M0, (float*)d_out);
}